// Round 9
// baseline (371.313 us; speedup 1.0000x reference)
//
#include <hip/hip_runtime.h>
#include <math.h>

// IDMRFLoss on MI355X — R9: sim never materialized. Three recompute GEMM
// passes (colmax / colsum / rowmax partials) over L2-resident swizzled
// operands; all cross-block reductions via non-atomic partial rows.
//
// Layer 0 (relu3_2): B=4, C=256, S=4096, weight 1.0
// Layer 1 (relu4_2): B=4, C=512, S=1024, weight 2.0 (style + content)
//
// Swizzled operand layout (per batch-slot, matrix [S][K] bf16):
//   elem(row,k) at ((row>>4)*(K/8) + (k>>3))*128 + (row&15)*8 + (k&7)
// MFMA C-layout per block (p0=by*128, q0=bx*128), wave w, tile (t,u), reg r:
//   p = p0 + (w&1)*64 + t*16 + quad*4 + r ; q = q0 + (w>>1)*64 + u*16 + lm
//
// Math (per z): c1 = 1/((1-colmax)/2+eps); log2 domain: c1L=c1*log2e,
// c0L=(2-c1)*log2e; colsum_q = sum_p 2^(c0L+c1L*v); fold c0L' = c0L-log2(colsum);
// kmax_p = 2^(max_q (c0L'+c1L*v)); loss = sum_z w_z * -log(mean_p kmax).

#define MRF_EPS 1e-5f
#define LOG2E 1.44269504088896340736f

typedef __attribute__((ext_vector_type(8))) short bf16x8;
typedef __attribute__((ext_vector_type(4))) float f32x4;
typedef unsigned short ushort_t;
struct __align__(16) ushort8_t { ushort_t v[8]; };

__device__ __forceinline__ ushort_t f2bf(float x) {
    unsigned u = __float_as_uint(x);
    u += 0x7FFFu + ((u >> 16) & 1u);
    return (ushort_t)(u >> 16);
}

// ---- stats: per position mean(tar), 1/||g-m||, 1/||t-m|| (single pass) ----
__global__ __launch_bounds__(256) void stats_kernel(
    const float* __restrict__ gen, const float* __restrict__ tar,
    float* __restrict__ mean, float* __restrict__ rg, float* __restrict__ rt,
    int C, int S) {
    int tid = threadIdx.x, pq = tid & 3, cs = tid >> 2;
    int b = blockIdx.y;
    int s0 = blockIdx.x * 16 + pq * 4;
    const float* g = gen + (size_t)b * C * S + s0;
    const float* t = tar + (size_t)b * C * S + s0;

    f32x4 st = {0.f, 0.f, 0.f, 0.f}, st2 = st, sg = st, sg2 = st;
    for (int c = cs; c < C; c += 64) {
        f32x4 tv = *(const f32x4*)(t + (size_t)c * S);
        f32x4 gv = *(const f32x4*)(g + (size_t)c * S);
        st += tv; st2 += tv * tv; sg += gv; sg2 += gv * gv;
    }
    __shared__ f32x4 red[4][4][64];
    __shared__ f32x4 red2[4][4][4];
    red[0][pq][cs] = st; red[1][pq][cs] = st2; red[2][pq][cs] = sg; red[3][pq][cs] = sg2;
    __syncthreads();
    if (tid < 64) {
        int s_ = tid >> 4, p_ = (tid >> 2) & 3, part = tid & 3;
        f32x4 s = red[s_][p_][part * 16];
#pragma unroll
        for (int j = 1; j < 16; j++) s += red[s_][p_][part * 16 + j];
        red2[s_][p_][part] = s;
    }
    __syncthreads();
    if (tid < 4) {
        f32x4 sts = red2[0][tid][0] + red2[0][tid][1] + red2[0][tid][2] + red2[0][tid][3];
        f32x4 st2s = red2[1][tid][0] + red2[1][tid][1] + red2[1][tid][2] + red2[1][tid][3];
        f32x4 sgs = red2[2][tid][0] + red2[2][tid][1] + red2[2][tid][2] + red2[2][tid][3];
        f32x4 sg2s = red2[3][tid][0] + red2[3][tid][1] + red2[3][tid][2] + red2[3][tid][3];
        f32x4 m, vrt, vrg;
        float invC = 1.f / (float)C;
#pragma unroll
        for (int e = 0; e < 4; e++) {
            float mm = sts[e] * invC;
            m[e] = mm;
            vrt[e] = rsqrtf(st2s[e] - mm * sts[e]);
            vrg[e] = rsqrtf(sg2s[e] - 2.f * mm * sgs[e] + mm * sts[e]);
        }
        int idx = b * S + blockIdx.x * 16 + tid * 4;
        *(f32x4*)(mean + idx) = m;
        *(f32x4*)(rt + idx) = vrt;
        *(f32x4*)(rg + idx) = vrg;
    }
}

// ---- apply: normalize + transpose -> swizzled MFMA layout bf16 (slot z) ----
__global__ __launch_bounds__(256) void apply_kernel(
    const float* __restrict__ gen, const float* __restrict__ tar,
    const float* __restrict__ mean, const float* __restrict__ rg, const float* __restrict__ rt,
    ushort_t* __restrict__ gnT, ushort_t* __restrict__ tnT, int C, int S) {
    int tid = threadIdx.x;
    int b = blockIdx.z;
    int s0 = blockIdx.x * 64, c0 = blockIdx.y * 64;
    const float* g = gen + (size_t)b * C * S;
    const float* t = tar + (size_t)b * C * S;
    int tx = tid & 63, tw = tid >> 6;
    int sidx = b * S + s0 + tx;
    float m = mean[sidx], rgv = rg[sidx], rtv = rt[sidx];

    __shared__ ushort_t tg[64][72], tt_[64][72];
#pragma unroll
    for (int i = 0; i < 16; i++) {
        int cl = tw * 16 + i;
        float gv = g[(size_t)(c0 + cl) * S + s0 + tx];
        float tv = t[(size_t)(c0 + cl) * S + s0 + tx];
        tg[tx][cl] = f2bf((gv - m) * rgv);
        tt_[tx][cl] = f2bf((tv - m) * rtv);
    }
    __syncthreads();
    int KC = C >> 3;
#pragma unroll
    for (int j = 0; j < 2; j++) {
        int p = j * 256 + tid;
        int s = p & 63, ch = p >> 6;
        int row = s0 + s;
        int r16 = row >> 4, lm = row & 15;
        size_t off = (size_t)b * S * C + (((size_t)r16 * KC + (c0 >> 3) + ch) * 16 + lm) * 8;
        *(ushort8_t*)(gnT + off) = *(const ushort8_t*)&tg[s][ch * 8];
        *(ushort8_t*)(tnT + off) = *(const ushort8_t*)&tt_[s][ch * 8];
    }
}

// ---- shared K-loop GEMM, 3 epilogue modes ----
// MODE 0: out = cmPart[R][S]  (column-max partials, R = 2*S/128)
// MODE 1: out = csPart[R][S]  (column-sum-of-2^ partials, coef = {c0L,c1L})
// MODE 2: out = rmPart[R][S]  (row affine-max partials per q-chunk, folded coef)
template <int K, int MODE>
__global__ __launch_bounds__(256) void gemm_pass(
    const ushort_t* __restrict__ A, const ushort_t* __restrict__ B,
    float* __restrict__ out, const float2* __restrict__ coef,
    int S, size_t abStride, size_t outStride, size_t coefStride) {
    int z = blockIdx.z;
    A += (size_t)z * abStride; B += (size_t)z * abStride;
    out += (size_t)z * outStride; coef += (size_t)z * coefStride;

    const int tid = threadIdx.x;
    const int lane = tid & 63, wave = tid >> 6;
    const int wm = (wave & 1) * 64, wn = (wave >> 1) * 64;
    const int lm = lane & 15, quad = lane >> 4;
    const int p0 = blockIdx.y * 128, q0 = blockIdx.x * 128;

    constexpr int KC = K / 8;
    constexpr int KS = K / 32;

    const ushort_t* Ab = A + ((size_t)((p0 + wm) >> 4) * KC + quad) * 128 + lm * 8;
    const ushort_t* Bb = B + ((size_t)((q0 + wn) >> 4) * KC + quad) * 128 + lm * 8;

    f32x4 acc[4][4];
#pragma unroll
    for (int t = 0; t < 4; t++)
#pragma unroll
        for (int u = 0; u < 4; u++) acc[t][u] = (f32x4){0.f, 0.f, 0.f, 0.f};

    bf16x8 a0[4], b0[4], a1[4], b1[4];
#pragma unroll
    for (int t = 0; t < 4; t++) {
        a0[t] = *(const bf16x8*)(Ab + (size_t)(t * KC) * 128);
        b0[t] = *(const bf16x8*)(Bb + (size_t)(t * KC) * 128);
    }
#pragma unroll
    for (int ks = 0; ks < KS; ks += 2) {
#pragma unroll
        for (int t = 0; t < 4; t++) {
            a1[t] = *(const bf16x8*)(Ab + (size_t)(t * KC + (ks + 1) * 4) * 128);
            b1[t] = *(const bf16x8*)(Bb + (size_t)(t * KC + (ks + 1) * 4) * 128);
        }
#pragma unroll
        for (int t = 0; t < 4; t++)
#pragma unroll
            for (int u = 0; u < 4; u++)
                acc[t][u] = __builtin_amdgcn_mfma_f32_16x16x32_bf16(a0[t], b0[u], acc[t][u], 0, 0, 0);
        if (ks + 2 < KS) {
#pragma unroll
            for (int t = 0; t < 4; t++) {
                a0[t] = *(const bf16x8*)(Ab + (size_t)(t * KC + (ks + 2) * 4) * 128);
                b0[t] = *(const bf16x8*)(Bb + (size_t)(t * KC + (ks + 2) * 4) * 128);
            }
        }
#pragma unroll
        for (int t = 0; t < 4; t++)
#pragma unroll
            for (int u = 0; u < 4; u++)
                acc[t][u] = __builtin_amdgcn_mfma_f32_16x16x32_bf16(a1[t], b1[u], acc[t][u], 0, 0, 0);
    }

    if constexpr (MODE == 0) {
        // column max partials: row r = by*2 + (wave&1)
        float cmax[4] = {-INFINITY, -INFINITY, -INFINITY, -INFINITY};
#pragma unroll
        for (int t = 0; t < 4; t++)
#pragma unroll
            for (int u = 0; u < 4; u++) {
                f32x4 v = acc[t][u];
                cmax[u] = fmaxf(cmax[u], fmaxf(fmaxf(v.x, v.y), fmaxf(v.z, v.w)));
            }
        int r = blockIdx.y * 2 + (wave & 1);
#pragma unroll
        for (int u = 0; u < 4; u++) {
            float m = cmax[u];
            m = fmaxf(m, __shfl_xor(m, 16, 64));
            m = fmaxf(m, __shfl_xor(m, 32, 64));
            if (lane < 16) out[(size_t)r * S + q0 + wn + u * 16 + lane] = m;
        }
    } else if constexpr (MODE == 1) {
        // column sum-of-2^ partials: same row indexing as MODE 0
        float2 cc[4];
#pragma unroll
        for (int u = 0; u < 4; u++) cc[u] = coef[q0 + wn + u * 16 + lm];
        float s[4] = {0.f, 0.f, 0.f, 0.f};
#pragma unroll
        for (int t = 0; t < 4; t++)
#pragma unroll
            for (int u = 0; u < 4; u++) {
                f32x4 v = acc[t][u];
                s[u] += exp2f(cc[u].x + cc[u].y * v.x) + exp2f(cc[u].x + cc[u].y * v.y)
                      + exp2f(cc[u].x + cc[u].y * v.z) + exp2f(cc[u].x + cc[u].y * v.w);
            }
        int r = blockIdx.y * 2 + (wave & 1);
#pragma unroll
        for (int u = 0; u < 4; u++) {
            float v = s[u];
            v += __shfl_xor(v, 16, 64);
            v += __shfl_xor(v, 32, 64);
            if (lane < 16) out[(size_t)r * S + q0 + wn + u * 16 + lane] = v;
        }
    } else {
        // row affine-max partials over this block's q-half: chunk = bx*2 + (wave>>1)
        float2 cc[4];
#pragma unroll
        for (int u = 0; u < 4; u++) cc[u] = coef[q0 + wn + u * 16 + lm];
        int qc = blockIdx.x * 2 + (wave >> 1);
#pragma unroll
        for (int t = 0; t < 4; t++) {
            f32x4 m = {-INFINITY, -INFINITY, -INFINITY, -INFINITY};
#pragma unroll
            for (int u = 0; u < 4; u++) {
                f32x4 v = acc[t][u];
#pragma unroll
                for (int r = 0; r < 4; r++)
                    m[r] = fmaxf(m[r], cc[u].x + cc[u].y * v[r]);
            }
#pragma unroll
            for (int off = 1; off < 16; off <<= 1)
#pragma unroll
                for (int r = 0; r < 4; r++)
                    m[r] = fmaxf(m[r], __shfl_xor(m[r], off, 64));
            if (lm == 0)
                *(f32x4*)(out + (size_t)qc * S + p0 + wm + t * 16 + quad * 4) = m;
        }
    }
}

// ---- reduce colmax partials -> log2 coef {c0L,c1L}; zero acc slot ----
__global__ __launch_bounds__(256) void colmax_reduce(
    const float* __restrict__ cmPart, float2* __restrict__ coef,
    float* __restrict__ accSlot, int S, int R, size_t cmStride) {
    int z = blockIdx.y;
    if (blockIdx.x == 0 && threadIdx.x == 0) accSlot[z] = 0.f;
    cmPart += (size_t)z * cmStride; coef += (size_t)z * S;
    int q = blockIdx.x * 256 + threadIdx.x;
    float m = cmPart[q];
    for (int r = 1; r < R; r++) m = fmaxf(m, cmPart[(size_t)r * S + q]);
    float c1 = 1.f / ((1.f - m) * 0.5f + MRF_EPS);
    coef[q] = make_float2((2.f - c1) * LOG2E, c1 * LOG2E);
}

// ---- fold colsum partials into coef: c0L' = c0L - log2(sum_r csPart) ----
__global__ __launch_bounds__(256) void coef_fold(
    const float* __restrict__ csPart, float2* __restrict__ coef,
    int S, int R, size_t csStride) {
    int z = blockIdx.y;
    csPart += (size_t)z * csStride; coef += (size_t)z * S;
    int q = blockIdx.x * 256 + threadIdx.x;
    float s = csPart[q];
    for (int r = 1; r < R; r++) s += csPart[(size_t)r * S + q];
    coef[q].x -= log2f(s);
}

// ---- final: per row max over q-chunk partials, exp2, block-sum -> acc ----
__global__ __launch_bounds__(256) void rowmax_final(
    const float* __restrict__ rmPart, float* __restrict__ acc,
    int S, int nChunks, size_t rmStride) {
    int z = blockIdx.y;
    rmPart += (size_t)z * rmStride;
    int p = blockIdx.x * 256 + threadIdx.x;
    float m = rmPart[p];
    for (int j = 1; j < nChunks; j++) m = fmaxf(m, rmPart[(size_t)j * S + p]);
    float v = exp2f(m);
    __shared__ float red[256];
    red[threadIdx.x] = v;
    __syncthreads();
    for (int h = 128; h > 0; h >>= 1) {
        if (threadIdx.x < h) red[threadIdx.x] += red[threadIdx.x + h];
        __syncthreads();
    }
    if (threadIdx.x == 0) atomicAdd(acc + z, red[0]);
}

__global__ void finalize_kernel(const float* __restrict__ acc, float* __restrict__ out) {
    float loss = 0.f;
    for (int b = 0; b < 4; b++) loss += -logf(acc[b] * (1.f / 4096.f));
    for (int b = 0; b < 4; b++) loss += -2.f * logf(acc[4 + b] * (1.f / 1024.f));
    out[0] = loss;
}

extern "C" void kernel_launch(void* const* d_in, const int* in_sizes, int n_in,
                              void* d_out, int out_size, void* d_ws, size_t ws_size,
                              hipStream_t stream) {
    const float* gen3 = (const float*)d_in[0];
    const float* tar3 = (const float*)d_in[1];
    const float* gen4 = (const float*)d_in[2];
    const float* tar4 = (const float*)d_in[3];

    char* wsb = (char*)d_ws;
    size_t off = 0;
    auto alloc = [&](size_t bytes) {
        void* p = wsb + off;
        off += (bytes + 255) & ~(size_t)255;
        return p;
    };
    ushort_t* gnT = (ushort_t*)alloc((size_t)4 * 4096 * 256 * 2);   // 8 MB
    ushort_t* tnT = (ushort_t*)alloc((size_t)4 * 4096 * 256 * 2);   // 8 MB
    float* part = (float*)alloc((size_t)4 * 64 * 4096 * 4);         // 4 MB (cm/cs shared)
    float* rmPart = (float*)alloc((size_t)4 * 64 * 4096 * 4);       // 4 MB
    float2* coef = (float2*)alloc(4 * 4096 * sizeof(float2));
    float* mean = (float*)alloc(4 * 4096 * 4);
    float* rg = (float*)alloc(4 * 4096 * 4);
    float* rt = (float*)alloc(4 * 4096 * 4);
    float* acc = (float*)alloc(64 * 4);
    // total ~24.3 MB

    // ---- layer 0: C=256, S=4096, z=4 ----
    {
        const int C = 256, S = 4096, R = 2 * (S / 128);
        const size_t abStr = (size_t)S * C, partStr = (size_t)R * S;
        stats_kernel<<<dim3(S / 16, 4), 256, 0, stream>>>(gen3, tar3, mean, rg, rt, C, S);
        apply_kernel<<<dim3(S / 64, C / 64, 4), 256, 0, stream>>>(
            gen3, tar3, mean, rg, rt, gnT, tnT, C, S);
        gemm_pass<256, 0><<<dim3(S / 128, S / 128, 4), 256, 0, stream>>>(
            tnT, gnT, part, nullptr, S, abStr, partStr, S);
        colmax_reduce<<<dim3(S / 256, 4), 256, 0, stream>>>(part, coef, acc, S, R, partStr);
        gemm_pass<256, 1><<<dim3(S / 128, S / 128, 4), 256, 0, stream>>>(
            tnT, gnT, part, coef, S, abStr, partStr, S);
        coef_fold<<<dim3(S / 256, 4), 256, 0, stream>>>(part, coef, S, R, partStr);
        gemm_pass<256, 2><<<dim3(S / 128, S / 128, 4), 256, 0, stream>>>(
            tnT, gnT, rmPart, coef, S, abStr, partStr, S);
        rowmax_final<<<dim3(S / 256, 4), 256, 0, stream>>>(rmPart, acc, S, R, partStr);
    }
    // ---- layer 1: C=512, S=1024, z=4 ----
    {
        const int C = 512, S = 1024, R = 2 * (S / 128);
        const size_t abStr = (size_t)S * C, partStr = (size_t)R * S;
        stats_kernel<<<dim3(S / 16, 4), 256, 0, stream>>>(gen4, tar4, mean, rg, rt, C, S);
        apply_kernel<<<dim3(S / 64, C / 64, 4), 256, 0, stream>>>(
            gen4, tar4, mean, rg, rt, gnT, tnT, C, S);
        gemm_pass<512, 0><<<dim3(S / 128, S / 128, 4), 256, 0, stream>>>(
            tnT, gnT, part, nullptr, S, abStr, partStr, S);
        colmax_reduce<<<dim3(S / 256, 4), 256, 0, stream>>>(part, coef, acc + 4, S, R, partStr);
        gemm_pass<512, 1><<<dim3(S / 128, S / 128, 4), 256, 0, stream>>>(
            tnT, gnT, part, coef, S, abStr, partStr, S);
        coef_fold<<<dim3(S / 256, 4), 256, 0, stream>>>(part, coef, S, R, partStr);
        gemm_pass<512, 2><<<dim3(S / 128, S / 128, 4), 256, 0, stream>>>(
            tnT, gnT, rmPart, coef, S, abStr, partStr, S);
        rowmax_final<<<dim3(S / 256, 4), 256, 0, stream>>>(rmPart, acc + 4, S, R, partStr);
    }
    finalize_kernel<<<1, 1, 0, stream>>>(acc, (float*)d_out);
}

// Round 10
// 286.552 us; speedup vs baseline: 1.2958x; 1.2958x over previous
//
#include <hip/hip_runtime.h>
#include <math.h>

// IDMRFLoss on MI355X — R10: R7 base (best, 275us) + widened gemm wave tile
// 64x128 (block 128x256) for layer3 to cut L2 frag-load bytes/FLOP by 25%.
// R9 proved the K-loop is L2-frag-load bound (59us with no stores).
//
// Layer 0 (relu3_2): B=4, C=256, S=4096, weight 1.0
// Layer 1 (relu4_2): B=4, C=512, S=1024, weight 2.0 (style + content)
//
// Swizzled operand layout (per batch-slot, matrix [S][K] bf16):
//   elem(row,k) at ((row>>4)*(K/8) + (k>>3))*128 + (row&15)*8 + (k&7)
// sim blocked bf16 layout (R7, per 128x128 q-block at (by,bx)):
//   elem(p,q) = (by*nQB+bx)*16384 + slot*4096 + (t*4+u)*256 + quad*64 + lm*4 + r
//   with by=p>>7, bx=q>>7, slot=((p>>6)&1)|(((q>>6)&1)<<1), t=(p>>4)&3,
//   u=(q>>4)&3, quad=(p>>2)&3, lm=q&15, r=p&3.
//
// Math (per z): c1 = 1/((1-colmax)/2+eps); log2 domain: c1L=c1*log2e,
// c0L=(2-c1)*log2e; colsum_q = sum_p 2^(c0L+c1L*v); fold c0L' = c0L-log2(colsum);
// kmax_p = 2^(max_q (c0L'+c1L*v)); loss = sum_z w_z * -log(mean_p kmax).

#define MRF_EPS 1e-5f
#define LOG2E 1.44269504088896340736f

typedef __attribute__((ext_vector_type(8))) short bf16x8;
typedef __attribute__((ext_vector_type(4))) float f32x4;
typedef unsigned short ushort_t;
struct __align__(8) ushort4_t { ushort_t x, y, z, w; };
struct __align__(16) ushort8_t { ushort_t v[8]; };

__device__ __forceinline__ ushort_t f2bf(float x) {
    unsigned u = __float_as_uint(x);
    u += 0x7FFFu + ((u >> 16) & 1u);
    return (ushort_t)(u >> 16);
}
__device__ __forceinline__ float bf2f(ushort_t u) {
    return __uint_as_float(((unsigned)u) << 16);
}

// ---- stats: per position mean(tar), 1/||g-m||, 1/||t-m|| (single pass) ----
__global__ __launch_bounds__(256) void stats_kernel(
    const float* __restrict__ gen, const float* __restrict__ tar,
    float* __restrict__ mean, float* __restrict__ rg, float* __restrict__ rt,
    int C, int S) {
    int tid = threadIdx.x, pq = tid & 3, cs = tid >> 2;
    int b = blockIdx.y;
    int s0 = blockIdx.x * 16 + pq * 4;
    const float* g = gen + (size_t)b * C * S + s0;
    const float* t = tar + (size_t)b * C * S + s0;

    f32x4 st = {0.f, 0.f, 0.f, 0.f}, st2 = st, sg = st, sg2 = st;
    for (int c = cs; c < C; c += 64) {
        f32x4 tv = *(const f32x4*)(t + (size_t)c * S);
        f32x4 gv = *(const f32x4*)(g + (size_t)c * S);
        st += tv; st2 += tv * tv; sg += gv; sg2 += gv * gv;
    }
    __shared__ f32x4 red[4][4][64];
    __shared__ f32x4 red2[4][4][4];
    red[0][pq][cs] = st; red[1][pq][cs] = st2; red[2][pq][cs] = sg; red[3][pq][cs] = sg2;
    __syncthreads();
    if (tid < 64) {
        int s_ = tid >> 4, p_ = (tid >> 2) & 3, part = tid & 3;
        f32x4 s = red[s_][p_][part * 16];
#pragma unroll
        for (int j = 1; j < 16; j++) s += red[s_][p_][part * 16 + j];
        red2[s_][p_][part] = s;
    }
    __syncthreads();
    if (tid < 4) {
        f32x4 sts = red2[0][tid][0] + red2[0][tid][1] + red2[0][tid][2] + red2[0][tid][3];
        f32x4 st2s = red2[1][tid][0] + red2[1][tid][1] + red2[1][tid][2] + red2[1][tid][3];
        f32x4 sgs = red2[2][tid][0] + red2[2][tid][1] + red2[2][tid][2] + red2[2][tid][3];
        f32x4 sg2s = red2[3][tid][0] + red2[3][tid][1] + red2[3][tid][2] + red2[3][tid][3];
        f32x4 m, vrt, vrg;
        float invC = 1.f / (float)C;
#pragma unroll
        for (int e = 0; e < 4; e++) {
            float mm = sts[e] * invC;
            m[e] = mm;
            vrt[e] = rsqrtf(st2s[e] - mm * sts[e]);
            vrg[e] = rsqrtf(sg2s[e] - 2.f * mm * sgs[e] + mm * sts[e]);
        }
        int idx = b * S + blockIdx.x * 16 + tid * 4;
        *(f32x4*)(mean + idx) = m;
        *(f32x4*)(rt + idx) = vrt;
        *(f32x4*)(rg + idx) = vrg;
    }
}

// ---- apply: normalize + transpose -> swizzled MFMA layout bf16 (slot z) ----
__global__ __launch_bounds__(256) void apply_kernel(
    const float* __restrict__ gen, const float* __restrict__ tar,
    const float* __restrict__ mean, const float* __restrict__ rg, const float* __restrict__ rt,
    ushort_t* __restrict__ gnT, ushort_t* __restrict__ tnT, int C, int S, int batchBase) {
    int tid = threadIdx.x;
    int slot = blockIdx.z, b = batchBase + slot;
    int s0 = blockIdx.x * 64, c0 = blockIdx.y * 64;
    const float* g = gen + (size_t)b * C * S;
    const float* t = tar + (size_t)b * C * S;
    int tx = tid & 63, tw = tid >> 6;
    int sidx = b * S + s0 + tx;
    float m = mean[sidx], rgv = rg[sidx], rtv = rt[sidx];

    __shared__ ushort_t tg[64][72], tt_[64][72];
#pragma unroll
    for (int i = 0; i < 16; i++) {
        int cl = tw * 16 + i;
        float gv = g[(size_t)(c0 + cl) * S + s0 + tx];
        float tv = t[(size_t)(c0 + cl) * S + s0 + tx];
        tg[tx][cl] = f2bf((gv - m) * rgv);
        tt_[tx][cl] = f2bf((tv - m) * rtv);
    }
    __syncthreads();
    int KC = C >> 3;
#pragma unroll
    for (int j = 0; j < 2; j++) {
        int p = j * 256 + tid;
        int s = p & 63, ch = p >> 6;
        int row = s0 + s;
        int r16 = row >> 4, lm = row & 15;
        size_t off = (size_t)slot * S * C + (((size_t)r16 * KC + (c0 >> 3) + ch) * 16 + lm) * 8;
        *(ushort8_t*)(gnT + off) = *(const ushort8_t*)&tg[s][ch * 8];
        *(ushort8_t*)(tnT + off) = *(const ushort8_t*)&tt_[s][ch * 8];
    }
}

// ---- MFMA GEMM, LDS-free, no atomics: sim (R7 layout) + colmax partials ----
// NU = u-tiles per wave: 4 -> block 128x128 (R7), 8 -> block 128x256 (wide).
template <int K, int NU>
__global__ __launch_bounds__(256) void gemm_mfma(
    const ushort_t* __restrict__ A, const ushort_t* __restrict__ B,
    ushort_t* __restrict__ sim, float* __restrict__ cmPart,
    int S, size_t abStride, size_t simStride, size_t cmStride) {
    int z = blockIdx.z;
    A += (size_t)z * abStride; B += (size_t)z * abStride;
    sim += (size_t)z * simStride; cmPart += (size_t)z * cmStride;

    const int tid = threadIdx.x;
    const int lane = tid & 63, wave = tid >> 6;
    const int wm = (wave & 1) * 64;
    const int wn = (wave >> 1) * (NU * 16);
    const int lm = lane & 15, quad = lane >> 4;
    const int QB = NU * 32;                     // block q-span
    const int p0 = blockIdx.y * 128, q0 = blockIdx.x * QB;

    constexpr int KC = K / 8;
    constexpr int KS = K / 32;

    const ushort_t* Ab = A + ((size_t)((p0 + wm) >> 4) * KC + quad) * 128 + lm * 8;
    const ushort_t* Bb = B + ((size_t)((q0 + wn) >> 4) * KC + quad) * 128 + lm * 8;

    f32x4 acc[4][NU];
#pragma unroll
    for (int t = 0; t < 4; t++)
#pragma unroll
        for (int u = 0; u < NU; u++) acc[t][u] = (f32x4){0.f, 0.f, 0.f, 0.f};

    bf16x8 a0[4], b0[NU], a1[4], b1[NU];
#pragma unroll
    for (int t = 0; t < 4; t++)
        a0[t] = *(const bf16x8*)(Ab + (size_t)(t * KC) * 128);
#pragma unroll
    for (int u = 0; u < NU; u++)
        b0[u] = *(const bf16x8*)(Bb + (size_t)(u * KC) * 128);
#pragma unroll
    for (int ks = 0; ks < KS; ks += 2) {
#pragma unroll
        for (int t = 0; t < 4; t++)
            a1[t] = *(const bf16x8*)(Ab + (size_t)(t * KC + (ks + 1) * 4) * 128);
#pragma unroll
        for (int u = 0; u < NU; u++)
            b1[u] = *(const bf16x8*)(Bb + (size_t)(u * KC + (ks + 1) * 4) * 128);
#pragma unroll
        for (int t = 0; t < 4; t++)
#pragma unroll
            for (int u = 0; u < NU; u++)
                acc[t][u] = __builtin_amdgcn_mfma_f32_16x16x32_bf16(a0[t], b0[u], acc[t][u], 0, 0, 0);
        if (ks + 2 < KS) {
#pragma unroll
            for (int t = 0; t < 4; t++)
                a0[t] = *(const bf16x8*)(Ab + (size_t)(t * KC + (ks + 2) * 4) * 128);
#pragma unroll
            for (int u = 0; u < NU; u++)
                b0[u] = *(const bf16x8*)(Bb + (size_t)(u * KC + (ks + 2) * 4) * 128);
        }
#pragma unroll
        for (int t = 0; t < 4; t++)
#pragma unroll
            for (int u = 0; u < NU; u++)
                acc[t][u] = __builtin_amdgcn_mfma_f32_16x16x32_bf16(a1[t], b1[u], acc[t][u], 0, 0, 0);
    }

    // epilogue: bf16 stores in R7 blocked layout + colmax partials
    int nQB = S >> 7;
    float cmax[NU];
#pragma unroll
    for (int u = 0; u < NU; u++) cmax[u] = -INFINITY;
#pragma unroll
    for (int u = 0; u < NU; u++) {
        int q = q0 + wn + u * 16;              // lm=0 base for this u-tile
        int bxg = q >> 7, qbit = (q >> 6) & 1;
#pragma unroll
        for (int t = 0; t < 4; t++) {
            size_t addr = ((size_t)(blockIdx.y * nQB + bxg)) * 16384
                        + (size_t)(((wave & 1) | (qbit << 1)) * 4096
                        + (t * 4 + (u & 3)) * 256 + quad * 64 + lm * 4);
            f32x4 v = acc[t][u];
            ushort4_t o;
            o.x = f2bf(v.x); o.y = f2bf(v.y); o.z = f2bf(v.z); o.w = f2bf(v.w);
            *(ushort4_t*)(sim + addr) = o;
            float mx = fmaxf(fmaxf(bf2f(o.x), bf2f(o.y)), fmaxf(bf2f(o.z), bf2f(o.w)));
            cmax[u] = fmaxf(cmax[u], mx);
        }
    }
    int r = blockIdx.y * 2 + (wave & 1);
#pragma unroll
    for (int u = 0; u < NU; u++) {
        float m = cmax[u];
        m = fmaxf(m, __shfl_xor(m, 16, 64));
        m = fmaxf(m, __shfl_xor(m, 32, 64));
        if (lane < 16) cmPart[(size_t)r * S + q0 + wn + u * 16 + lane] = m;
    }
}

// ---- reduce colmax partials -> log2 coef {c0L,c1L}; zero colsum + acc slot ----
__global__ __launch_bounds__(256) void colmax_reduce(
    const float* __restrict__ cmPart, float2* __restrict__ coef,
    float* __restrict__ colsum, float* __restrict__ accSlot,
    int S, int R, size_t cmStride) {
    int z = blockIdx.y;
    if (blockIdx.x == 0 && threadIdx.x == 0) accSlot[z] = 0.f;
    cmPart += (size_t)z * cmStride; coef += (size_t)z * S; colsum += (size_t)z * S;
    int q = blockIdx.x * 256 + threadIdx.x;
    float m = cmPart[q];
    for (int r = 1; r < R; r++) m = fmaxf(m, cmPart[(size_t)r * S + q]);
    float c1 = 1.f / ((1.f - m) * 0.5f + MRF_EPS);
    coef[q] = make_float2((2.f - c1) * LOG2E, c1 * LOG2E);
    colsum[q] = 0.f;
}

// ---- column sums of dist (2^x domain), R7 version ----
__global__ __launch_bounds__(256) void colsum_kernel(
    const ushort_t* __restrict__ sim, const float2* __restrict__ coef,
    float* __restrict__ colsum, int S, size_t simStride) {
    int z = blockIdx.z;
    sim += (size_t)z * simStride; coef += (size_t)z * S; colsum += (size_t)z * S;
    int tid = threadIdx.x, lane = tid & 63;
    int u = lane >> 4, lm = lane & 15;
    int sub = (tid >> 6) & 1, cg = tid >> 7;
    int bx = blockIdx.x, by = blockIdx.y;
    int nQB = S >> 7;
    int q = bx * 128 + cg * 64 + u * 16 + lm;
    float2 cc = coef[q];
    float c0 = cc.x, c1 = cc.y;
    const ushort_t* base = sim + ((size_t)(by * nQB + bx)) * 16384
                         + (size_t)((sub | (cg << 1)) * 4096 + u * 256 + lm * 4);
    float s = 0.f;
#pragma unroll
    for (int t = 0; t < 4; t++)
#pragma unroll
        for (int quad = 0; quad < 4; quad++) {
            ushort4_t w = *(const ushort4_t*)(base + t * 1024 + quad * 64);
            s += exp2f(c0 + c1 * bf2f(w.x)) + exp2f(c0 + c1 * bf2f(w.y))
               + exp2f(c0 + c1 * bf2f(w.z)) + exp2f(c0 + c1 * bf2f(w.w));
        }
    atomicAdd(colsum + q, s);
}

// ---- fold colsum into coef: c0L' = c0L - log2(colsum) ----
__global__ __launch_bounds__(256) void coef_fold(
    float2* __restrict__ coef, const float* __restrict__ colsum, int S) {
    int z = blockIdx.y;
    coef += (size_t)z * S; colsum += (size_t)z * S;
    int q = blockIdx.x * 256 + threadIdx.x;
    coef[q].x -= log2f(colsum[q]);
}

// ---- row max of affine args (exp2 once per row), R7 version ----
__global__ __launch_bounds__(256) void rowmax_kernel(
    const ushort_t* __restrict__ sim, const float2* __restrict__ coef,
    float* __restrict__ acc, int S, size_t simStride) {
    int z = blockIdx.y;
    sim += (size_t)z * simStride; coef += (size_t)z * S;
    int wave = threadIdx.x >> 6, lane = threadIdx.x & 63;
    int g = blockIdx.x * 4 + wave;
    int by = g >> 5, rem = g & 31;
    int sub = rem >> 4, t = (rem >> 2) & 3, quad = rem & 3;
    int u = lane >> 4, lm = lane & 15;
    int nQB = S >> 7;
    f32x4 m = {-INFINITY, -INFINITY, -INFINITY, -INFINITY};
    for (int bx = 0; bx < nQB; bx++) {
#pragma unroll
        for (int cg = 0; cg < 2; cg++) {
            int q = bx * 128 + cg * 64 + u * 16 + lm;
            float2 cc = coef[q];
            const ushort_t* ptr = sim + ((size_t)(by * nQB + bx)) * 16384
                                + (size_t)((sub | (cg << 1)) * 4096 + (t * 4 + u) * 256 + quad * 64 + lm * 4);
            ushort4_t w = *(const ushort4_t*)ptr;
            m[0] = fmaxf(m[0], cc.x + cc.y * bf2f(w.x));
            m[1] = fmaxf(m[1], cc.x + cc.y * bf2f(w.y));
            m[2] = fmaxf(m[2], cc.x + cc.y * bf2f(w.z));
            m[3] = fmaxf(m[3], cc.x + cc.y * bf2f(w.w));
        }
    }
#pragma unroll
    for (int off = 32; off >= 1; off >>= 1)
#pragma unroll
        for (int e = 0; e < 4; e++)
            m[e] = fmaxf(m[e], __shfl_xor(m[e], off, 64));
    __shared__ float partial[4];
    if (lane == 0)
        partial[wave] = exp2f(m[0]) + exp2f(m[1]) + exp2f(m[2]) + exp2f(m[3]);
    __syncthreads();
    if (threadIdx.x == 0)
        atomicAdd(acc + z, partial[0] + partial[1] + partial[2] + partial[3]);
}

__global__ void finalize_kernel(const float* __restrict__ acc, float* __restrict__ out) {
    float loss = 0.f;
    for (int b = 0; b < 4; b++) loss += -logf(acc[b] * (1.f / 4096.f));
    for (int b = 0; b < 4; b++) loss += -2.f * logf(acc[4 + b] * (1.f / 1024.f));
    out[0] = loss;
}

extern "C" void kernel_launch(void* const* d_in, const int* in_sizes, int n_in,
                              void* d_out, int out_size, void* d_ws, size_t ws_size,
                              hipStream_t stream) {
    const float* gen3 = (const float*)d_in[0];
    const float* tar3 = (const float*)d_in[1];
    const float* gen4 = (const float*)d_in[2];
    const float* tar4 = (const float*)d_in[3];

    const int zB3 = (ws_size >= (size_t)170 * 1024 * 1024) ? 4 : 2;

    char* wsb = (char*)d_ws;
    size_t off = 0;
    auto alloc = [&](size_t bytes) {
        void* p = wsb + off;
        off += (bytes + 255) & ~(size_t)255;
        return p;
    };
    ushort_t* sim = (ushort_t*)alloc((size_t)zB3 * 4096 * 4096 * 2);
    ushort_t* gnT = (ushort_t*)alloc((size_t)zB3 * 4096 * 256 * 2);
    ushort_t* tnT = (ushort_t*)alloc((size_t)zB3 * 4096 * 256 * 2);
    float* cmPart = (float*)alloc((size_t)zB3 * 64 * 4096 * 4);
    float2* coef = (float2*)alloc(4 * 4096 * sizeof(float2));
    float* colsum = (float*)alloc(4 * 4096 * 4);
    float* mean = (float*)alloc(4 * 4096 * 4);
    float* rg = (float*)alloc(4 * 4096 * 4);
    float* rt = (float*)alloc(4 * 4096 * 4);
    float* acc = (float*)alloc(64 * 4);

    // ---- layer 0: C=256, S=4096 ----
    {
        const int C = 256, S = 4096, R = 2 * (S / 128);
        stats_kernel<<<dim3(S / 16, 4), 256, 0, stream>>>(gen3, tar3, mean, rg, rt, C, S);
        for (int r0 = 0; r0 < 4; r0 += zB3) {
            apply_kernel<<<dim3(S / 64, C / 64, zB3), 256, 0, stream>>>(
                gen3, tar3, mean, rg, rt, gnT, tnT, C, S, r0);
            gemm_mfma<256, 8><<<dim3(S / 256, S / 128, zB3), 256, 0, stream>>>(
                tnT, gnT, sim, cmPart, S, (size_t)S * C, (size_t)S * S, (size_t)R * S);
            colmax_reduce<<<dim3(S / 256, zB3), 256, 0, stream>>>(
                cmPart, coef, colsum, acc + r0, S, R, (size_t)R * S);
            colsum_kernel<<<dim3(S / 128, S / 128, zB3), 256, 0, stream>>>(
                sim, coef, colsum, S, (size_t)S * S);
            coef_fold<<<dim3(S / 256, zB3), 256, 0, stream>>>(coef, colsum, S);
            rowmax_kernel<<<dim3(S / 16, zB3), 256, 0, stream>>>(
                sim, coef, acc + r0, S, (size_t)S * S);
        }
    }
    // ---- layer 1: C=512, S=1024, z=4, 128x128 tile (occupancy) ----
    {
        const int C = 512, S = 1024, R = 2 * (S / 128);
        stats_kernel<<<dim3(S / 16, 4), 256, 0, stream>>>(gen4, tar4, mean, rg, rt, C, S);
        apply_kernel<<<dim3(S / 64, C / 64, 4), 256, 0, stream>>>(
            gen4, tar4, mean, rg, rt, gnT, tnT, C, S, 0);
        gemm_mfma<512, 4><<<dim3(S / 128, S / 128, 4), 256, 0, stream>>>(
            tnT, gnT, sim, cmPart, S, (size_t)S * C, (size_t)S * S, (size_t)R * S);
        colmax_reduce<<<dim3(S / 256, 4), 256, 0, stream>>>(
            cmPart, coef, colsum, acc + 4, S, R, (size_t)R * S);
        colsum_kernel<<<dim3(S / 128, S / 128, 4), 256, 0, stream>>>(
            sim, coef, colsum, S, (size_t)S * S);
        coef_fold<<<dim3(S / 256, 4), 256, 0, stream>>>(coef, colsum, S);
        rowmax_kernel<<<dim3(S / 16, 4), 256, 0, stream>>>(
            sim, coef, acc + 4, S, (size_t)S * S);
    }
    finalize_kernel<<<1, 1, 0, stream>>>(acc, (float*)d_out);
}

// Round 11
// 273.921 us; speedup vs baseline: 1.3556x; 1.0461x over previous
//
#include <hip/hip_runtime.h>
#include <math.h>

// IDMRFLoss on MI355X — R11: R7 bodies (best, 275us), both layers merged
// per phase -> 7 launches total (was 16). coef_fold folded into rowmax.
//
// Layer 0 (relu3_2): B=4, C=256, S=4096, weight 1.0
// Layer 1 (relu4_2): B=4, C=512, S=1024, weight 2.0 (style + content)
//
// Swizzled operand layout (per batch, matrix [S][K] bf16):
//   elem(row,k) at ((row>>4)*(K/8) + (k>>3))*128 + (row&15)*8 + (k&7)
// sim blocked bf16 layout (per 128x128 block at (by,bx)):
//   elem = (by*nQB+bx)*16384 + slot*4096 + (t*4+u)*256 + quad*64 + lm*4 + r
//   p = by*128+(slot&1)*64+t*16+quad*4+r ; q = bx*128+(slot>>1)*64+u*16+lm
//
// Math (per combo): c1 = 1/((1-colmax)/2+eps); log2 domain c1L=c1*log2e,
// c0L=(2-c1)*log2e; colsum_q = sum_p 2^(c0L+c1L*v);
// kmax_p = 2^(max_q (c0L - log2(colsum_q) + c1L*v)); loss = sum -w*log(mean kmax).

#define MRF_EPS 1e-5f
#define LOG2E 1.44269504088896340736f

typedef __attribute__((ext_vector_type(8))) short bf16x8;
typedef __attribute__((ext_vector_type(4))) float f32x4;
typedef unsigned short ushort_t;
struct __align__(8) ushort4_t { ushort_t x, y, z, w; };
struct __align__(16) ushort8_t { ushort_t v[8]; };

__device__ __forceinline__ ushort_t f2bf(float x) {
    unsigned u = __float_as_uint(x);
    u += 0x7FFFu + ((u >> 16) & 1u);
    return (ushort_t)(u >> 16);
}
__device__ __forceinline__ float bf2f(ushort_t u) {
    return __uint_as_float(((unsigned)u) << 16);
}

// ================= stats =================
__global__ __launch_bounds__(256) void stats_all(
    const float* __restrict__ gen3, const float* __restrict__ tar3,
    const float* __restrict__ gen4, const float* __restrict__ tar4,
    float* __restrict__ mean3, float* __restrict__ rg3, float* __restrict__ rt3,
    float* __restrict__ mean4, float* __restrict__ rg4, float* __restrict__ rt4) {
    const float *gen, *tar; float *mean, *rg, *rt; int C, S, b, bx;
    int bid = blockIdx.x;
    if (bid < 256) {            // layer4 first (heavier per block)
        C = 512; S = 1024; b = bid >> 6; bx = bid & 63;
        gen = gen4; tar = tar4; mean = mean4; rg = rg4; rt = rt4;
    } else {
        bid -= 256;
        C = 256; S = 4096; b = bid >> 8; bx = bid & 255;
        gen = gen3; tar = tar3; mean = mean3; rg = rg3; rt = rt3;
    }
    int tid = threadIdx.x, pq = tid & 3, cs = tid >> 2;
    int s0 = bx * 16 + pq * 4;
    const float* g = gen + (size_t)b * C * S + s0;
    const float* t = tar + (size_t)b * C * S + s0;

    f32x4 st = {0.f, 0.f, 0.f, 0.f}, st2 = st, sg = st, sg2 = st;
    for (int c = cs; c < C; c += 64) {
        f32x4 tv = *(const f32x4*)(t + (size_t)c * S);
        f32x4 gv = *(const f32x4*)(g + (size_t)c * S);
        st += tv; st2 += tv * tv; sg += gv; sg2 += gv * gv;
    }
    __shared__ f32x4 red[4][4][64];
    __shared__ f32x4 red2[4][4][4];
    red[0][pq][cs] = st; red[1][pq][cs] = st2; red[2][pq][cs] = sg; red[3][pq][cs] = sg2;
    __syncthreads();
    if (tid < 64) {
        int s_ = tid >> 4, p_ = (tid >> 2) & 3, part = tid & 3;
        f32x4 s = red[s_][p_][part * 16];
#pragma unroll
        for (int j = 1; j < 16; j++) s += red[s_][p_][part * 16 + j];
        red2[s_][p_][part] = s;
    }
    __syncthreads();
    if (tid < 4) {
        f32x4 sts = red2[0][tid][0] + red2[0][tid][1] + red2[0][tid][2] + red2[0][tid][3];
        f32x4 st2s = red2[1][tid][0] + red2[1][tid][1] + red2[1][tid][2] + red2[1][tid][3];
        f32x4 sgs = red2[2][tid][0] + red2[2][tid][1] + red2[2][tid][2] + red2[2][tid][3];
        f32x4 sg2s = red2[3][tid][0] + red2[3][tid][1] + red2[3][tid][2] + red2[3][tid][3];
        f32x4 m, vrt, vrg;
        float invC = 1.f / (float)C;
#pragma unroll
        for (int e = 0; e < 4; e++) {
            float mm = sts[e] * invC;
            m[e] = mm;
            vrt[e] = rsqrtf(st2s[e] - mm * sts[e]);
            vrg[e] = rsqrtf(sg2s[e] - 2.f * mm * sgs[e] + mm * sts[e]);
        }
        int idx = b * S + bx * 16 + tid * 4;
        *(f32x4*)(mean + idx) = m;
        *(f32x4*)(rt + idx) = vrt;
        *(f32x4*)(rg + idx) = vrg;
    }
}

// ================= apply =================
__global__ __launch_bounds__(256) void apply_all(
    const float* __restrict__ gen3, const float* __restrict__ tar3,
    const float* __restrict__ gen4, const float* __restrict__ tar4,
    const float* __restrict__ mean3, const float* __restrict__ rg3, const float* __restrict__ rt3,
    const float* __restrict__ mean4, const float* __restrict__ rg4, const float* __restrict__ rt4,
    ushort_t* __restrict__ gnT3, ushort_t* __restrict__ tnT3,
    ushort_t* __restrict__ gnT4, ushort_t* __restrict__ tnT4) {
    const float *gen, *tar, *mean, *rg, *rt; ushort_t *gnT, *tnT;
    int C, S, b, sxb, cyb;
    int bid = blockIdx.x;
    if (bid < 512) {            // layer4: 4 z * (16 x 8)
        C = 512; S = 1024; b = bid >> 7; int rem = bid & 127;
        cyb = rem >> 4; sxb = rem & 15;
        gen = gen4; tar = tar4; mean = mean4; rg = rg4; rt = rt4; gnT = gnT4; tnT = tnT4;
    } else {                    // layer3: 4 z * (64 x 4)
        bid -= 512;
        C = 256; S = 4096; b = bid >> 8; int rem = bid & 255;
        cyb = rem >> 6; sxb = rem & 63;
        gen = gen3; tar = tar3; mean = mean3; rg = rg3; rt = rt3; gnT = gnT3; tnT = tnT3;
    }
    int tid = threadIdx.x;
    int s0 = sxb * 64, c0 = cyb * 64;
    const float* g = gen + (size_t)b * C * S;
    const float* t = tar + (size_t)b * C * S;
    int tx = tid & 63, tw = tid >> 6;
    int sidx = b * S + s0 + tx;
    float m = mean[sidx], rgv = rg[sidx], rtv = rt[sidx];

    __shared__ ushort_t tg[64][72], tt_[64][72];
#pragma unroll
    for (int i = 0; i < 16; i++) {
        int cl = tw * 16 + i;
        float gv = g[(size_t)(c0 + cl) * S + s0 + tx];
        float tv = t[(size_t)(c0 + cl) * S + s0 + tx];
        tg[tx][cl] = f2bf((gv - m) * rgv);
        tt_[tx][cl] = f2bf((tv - m) * rtv);
    }
    __syncthreads();
    int KC = C >> 3;
#pragma unroll
    for (int j = 0; j < 2; j++) {
        int p = j * 256 + tid;
        int s = p & 63, ch = p >> 6;
        int row = s0 + s;
        int r16 = row >> 4, lm = row & 15;
        size_t off = (size_t)b * S * C + (((size_t)r16 * KC + (c0 >> 3) + ch) * 16 + lm) * 8;
        *(ushort8_t*)(gnT + off) = *(const ushort8_t*)&tg[s][ch * 8];
        *(ushort8_t*)(tnT + off) = *(const ushort8_t*)&tt_[s][ch * 8];
    }
}

// ================= gemm (R7 body, NU=4) =================
template <int K>
__device__ __forceinline__ void gemm_body(
    const ushort_t* __restrict__ A, const ushort_t* __restrict__ B,
    ushort_t* __restrict__ sim, float* __restrict__ cmPart,
    int S, int bx, int by) {
    const int tid = threadIdx.x;
    const int lane = tid & 63, wave = tid >> 6;
    const int wm = (wave & 1) * 64, wn = (wave >> 1) * 64;
    const int lm = lane & 15, quad = lane >> 4;
    const int p0 = by * 128, q0 = bx * 128;

    constexpr int KC = K / 8;
    constexpr int KS = K / 32;

    const ushort_t* Ab = A + ((size_t)((p0 + wm) >> 4) * KC + quad) * 128 + lm * 8;
    const ushort_t* Bb = B + ((size_t)((q0 + wn) >> 4) * KC + quad) * 128 + lm * 8;

    f32x4 acc[4][4];
#pragma unroll
    for (int t = 0; t < 4; t++)
#pragma unroll
        for (int u = 0; u < 4; u++) acc[t][u] = (f32x4){0.f, 0.f, 0.f, 0.f};

    bf16x8 a0[4], b0[4], a1[4], b1[4];
#pragma unroll
    for (int t = 0; t < 4; t++) {
        a0[t] = *(const bf16x8*)(Ab + (size_t)(t * KC) * 128);
        b0[t] = *(const bf16x8*)(Bb + (size_t)(t * KC) * 128);
    }
#pragma unroll
    for (int ks = 0; ks < KS; ks += 2) {
#pragma unroll
        for (int t = 0; t < 4; t++) {
            a1[t] = *(const bf16x8*)(Ab + (size_t)(t * KC + (ks + 1) * 4) * 128);
            b1[t] = *(const bf16x8*)(Bb + (size_t)(t * KC + (ks + 1) * 4) * 128);
        }
#pragma unroll
        for (int t = 0; t < 4; t++)
#pragma unroll
            for (int u = 0; u < 4; u++)
                acc[t][u] = __builtin_amdgcn_mfma_f32_16x16x32_bf16(a0[t], b0[u], acc[t][u], 0, 0, 0);
        if (ks + 2 < KS) {
#pragma unroll
            for (int t = 0; t < 4; t++) {
                a0[t] = *(const bf16x8*)(Ab + (size_t)(t * KC + (ks + 2) * 4) * 128);
                b0[t] = *(const bf16x8*)(Bb + (size_t)(t * KC + (ks + 2) * 4) * 128);
            }
        }
#pragma unroll
        for (int t = 0; t < 4; t++)
#pragma unroll
            for (int u = 0; u < 4; u++)
                acc[t][u] = __builtin_amdgcn_mfma_f32_16x16x32_bf16(a1[t], b1[u], acc[t][u], 0, 0, 0);
    }

    int nQB = S >> 7;
    size_t base = ((size_t)(by * nQB + bx)) * 16384
                + (size_t)(wave * 4096 + quad * 64 + lm * 4);
    float cmax[4] = {-INFINITY, -INFINITY, -INFINITY, -INFINITY};
#pragma unroll
    for (int t = 0; t < 4; t++)
#pragma unroll
        for (int u = 0; u < 4; u++) {
            f32x4 v = acc[t][u];
            ushort4_t o;
            o.x = f2bf(v.x); o.y = f2bf(v.y); o.z = f2bf(v.z); o.w = f2bf(v.w);
            *(ushort4_t*)(sim + base + (t * 4 + u) * 256) = o;
            float mx = fmaxf(fmaxf(bf2f(o.x), bf2f(o.y)), fmaxf(bf2f(o.z), bf2f(o.w)));
            cmax[u] = fmaxf(cmax[u], mx);
        }
    int r = by * 2 + (wave & 1);
#pragma unroll
    for (int u = 0; u < 4; u++) {
        float m = cmax[u];
        m = fmaxf(m, __shfl_xor(m, 16, 64));
        m = fmaxf(m, __shfl_xor(m, 32, 64));
        if (lane < 16) cmPart[(size_t)r * S + q0 + wn + u * 16 + lane] = m;
    }
}

__global__ __launch_bounds__(256) void gemm_all(
    const ushort_t* __restrict__ tnT3, const ushort_t* __restrict__ gnT3,
    ushort_t* __restrict__ sim3, float* __restrict__ cmPart3,
    const ushort_t* __restrict__ tnT4, const ushort_t* __restrict__ gnT4,
    ushort_t* __restrict__ sim4, float* __restrict__ cmPart4) {
    int bid = blockIdx.x;
    if (bid < 256) {            // layer4 first (2x K per block)
        int z = bid >> 6, rem = bid & 63, by = rem >> 3, bx = rem & 7;
        gemm_body<512>(tnT4 + (size_t)z * 524288, gnT4 + (size_t)z * 524288,
                       sim4 + (size_t)z * 1048576, cmPart4 + (size_t)z * 16384,
                       1024, bx, by);
    } else {
        bid -= 256;
        int z = bid >> 10, rem = bid & 1023, by = rem >> 5, bx = rem & 31;
        gemm_body<256>(tnT3 + (size_t)z * 1048576, gnT3 + (size_t)z * 1048576,
                       sim3 + (size_t)z * 16777216, cmPart3 + (size_t)z * 262144,
                       4096, bx, by);
    }
}

// ================= colmax reduce -> coef, zero colsum + acc =================
__global__ __launch_bounds__(256) void colmax_reduce_all(
    const float* __restrict__ cmPart3, float2* __restrict__ coef3, float* __restrict__ colsum3,
    const float* __restrict__ cmPart4, float2* __restrict__ coef4, float* __restrict__ colsum4,
    float* __restrict__ acc) {
    const float* cmPart; float2* coef; float* colsum; int S, R, qb, accIdx;
    int bid = blockIdx.x;
    if (bid < 16) {             // layer4: 4 z * 4 blocks
        int z = bid >> 2; qb = bid & 3; S = 1024; R = 16; accIdx = 4 + z;
        cmPart = cmPart4 + (size_t)z * 16384; coef = coef4 + (size_t)z * 1024;
        colsum = colsum4 + (size_t)z * 1024;
    } else {
        bid -= 16;
        int z = bid >> 4; qb = bid & 15; S = 4096; R = 64; accIdx = z;
        cmPart = cmPart3 + (size_t)z * 262144; coef = coef3 + (size_t)z * 4096;
        colsum = colsum3 + (size_t)z * 4096;
    }
    if (qb == 0 && threadIdx.x == 0) acc[accIdx] = 0.f;
    int q = qb * 256 + threadIdx.x;
    float m = cmPart[q];
    for (int r = 1; r < R; r++) m = fmaxf(m, cmPart[(size_t)r * S + q]);
    float c1 = 1.f / ((1.f - m) * 0.5f + MRF_EPS);
    coef[q] = make_float2((2.f - c1) * LOG2E, c1 * LOG2E);
    colsum[q] = 0.f;
}

// ================= colsum =================
__global__ __launch_bounds__(256) void colsum_all(
    const ushort_t* __restrict__ sim3, const float2* __restrict__ coef3, float* __restrict__ colsum3,
    const ushort_t* __restrict__ sim4, const float2* __restrict__ coef4, float* __restrict__ colsum4) {
    const ushort_t* sim; const float2* coef; float* colsum; int S, bx, by;
    int bid = blockIdx.x;
    if (bid < 256) {            // layer4: 4 z * (8 x 8)
        int z = bid >> 6, rem = bid & 63; by = rem >> 3; bx = rem & 7; S = 1024;
        sim = sim4 + (size_t)z * 1048576; coef = coef4 + (size_t)z * 1024;
        colsum = colsum4 + (size_t)z * 1024;
    } else {
        bid -= 256;
        int z = bid >> 10, rem = bid & 1023; by = rem >> 5; bx = rem & 31; S = 4096;
        sim = sim3 + (size_t)z * 16777216; coef = coef3 + (size_t)z * 4096;
        colsum = colsum3 + (size_t)z * 4096;
    }
    int tid = threadIdx.x, lane = tid & 63;
    int u = lane >> 4, lm = lane & 15;
    int sub = (tid >> 6) & 1, cg = tid >> 7;
    int nQB = S >> 7;
    int q = bx * 128 + cg * 64 + u * 16 + lm;
    float2 cc = coef[q];
    float c0 = cc.x, c1 = cc.y;
    const ushort_t* base = sim + ((size_t)(by * nQB + bx)) * 16384
                         + (size_t)((sub | (cg << 1)) * 4096 + u * 256 + lm * 4);
    float s = 0.f;
#pragma unroll
    for (int t = 0; t < 4; t++)
#pragma unroll
        for (int quad = 0; quad < 4; quad++) {
            ushort4_t w = *(const ushort4_t*)(base + t * 1024 + quad * 64);
            s += exp2f(c0 + c1 * bf2f(w.x)) + exp2f(c0 + c1 * bf2f(w.y))
               + exp2f(c0 + c1 * bf2f(w.z)) + exp2f(c0 + c1 * bf2f(w.w));
        }
    atomicAdd(colsum + q, s);
}

// ================= rowmax (inline fold: c0' = c0 - log2(colsum)) =================
__global__ __launch_bounds__(256) void rowmax_all(
    const ushort_t* __restrict__ sim3, const float2* __restrict__ coef3, const float* __restrict__ colsum3,
    const ushort_t* __restrict__ sim4, const float2* __restrict__ coef4, const float* __restrict__ colsum4,
    float* __restrict__ acc) {
    const ushort_t* sim; const float2* coef; const float* colsum;
    int S, blk; float* accSlot;
    int bid = blockIdx.x;
    if (bid < 1024) {           // layer3 first (4x q-scan per block)
        int z = bid >> 8; blk = bid & 255; S = 4096; accSlot = acc + z;
        sim = sim3 + (size_t)z * 16777216; coef = coef3 + (size_t)z * 4096;
        colsum = colsum3 + (size_t)z * 4096;
    } else {
        bid -= 1024;
        int z = bid >> 6; blk = bid & 63; S = 1024; accSlot = acc + 4 + z;
        sim = sim4 + (size_t)z * 1048576; coef = coef4 + (size_t)z * 1024;
        colsum = colsum4 + (size_t)z * 1024;
    }
    int wave = threadIdx.x >> 6, lane = threadIdx.x & 63;
    int g = blk * 4 + wave;
    int by = g >> 5, rem = g & 31;
    int sub = rem >> 4, t = (rem >> 2) & 3, quad = rem & 3;
    int u = lane >> 4, lm = lane & 15;
    int nQB = S >> 7;
    f32x4 m = {-INFINITY, -INFINITY, -INFINITY, -INFINITY};
    for (int bx = 0; bx < nQB; bx++) {
#pragma unroll
        for (int cg = 0; cg < 2; cg++) {
            int q = bx * 128 + cg * 64 + u * 16 + lm;
            float2 cc = coef[q];
            float c0p = cc.x - log2f(colsum[q]);
            const ushort_t* ptr = sim + ((size_t)(by * nQB + bx)) * 16384
                                + (size_t)((sub | (cg << 1)) * 4096 + (t * 4 + u) * 256 + quad * 64 + lm * 4);
            ushort4_t w = *(const ushort4_t*)ptr;
            m[0] = fmaxf(m[0], c0p + cc.y * bf2f(w.x));
            m[1] = fmaxf(m[1], c0p + cc.y * bf2f(w.y));
            m[2] = fmaxf(m[2], c0p + cc.y * bf2f(w.z));
            m[3] = fmaxf(m[3], c0p + cc.y * bf2f(w.w));
        }
    }
#pragma unroll
    for (int off = 32; off >= 1; off >>= 1)
#pragma unroll
        for (int e = 0; e < 4; e++)
            m[e] = fmaxf(m[e], __shfl_xor(m[e], off, 64));
    __shared__ float partial[4];
    if (lane == 0)
        partial[wave] = exp2f(m[0]) + exp2f(m[1]) + exp2f(m[2]) + exp2f(m[3]);
    __syncthreads();
    if (threadIdx.x == 0)
        atomicAdd(accSlot, partial[0] + partial[1] + partial[2] + partial[3]);
}

__global__ void finalize_kernel(const float* __restrict__ acc, float* __restrict__ out) {
    float loss = 0.f;
    for (int b = 0; b < 4; b++) loss += -logf(acc[b] * (1.f / 4096.f));
    for (int b = 0; b < 4; b++) loss += -2.f * logf(acc[4 + b] * (1.f / 1024.f));
    out[0] = loss;
}

extern "C" void kernel_launch(void* const* d_in, const int* in_sizes, int n_in,
                              void* d_out, int out_size, void* d_ws, size_t ws_size,
                              hipStream_t stream) {
    const float* gen3 = (const float*)d_in[0];
    const float* tar3 = (const float*)d_in[1];
    const float* gen4 = (const float*)d_in[2];
    const float* tar4 = (const float*)d_in[3];

    char* wsb = (char*)d_ws;
    size_t off = 0;
    auto alloc = [&](size_t bytes) {
        void* p = wsb + off;
        off += (bytes + 255) & ~(size_t)255;
        return p;
    };
    // layer3 (z=4): S=4096, C=256, R=64
    ushort_t* sim3 = (ushort_t*)alloc((size_t)4 * 16777216 * 2);   // 134.2 MB
    ushort_t* gnT3 = (ushort_t*)alloc((size_t)4 * 1048576 * 2);    // 8.4 MB
    ushort_t* tnT3 = (ushort_t*)alloc((size_t)4 * 1048576 * 2);    // 8.4 MB
    float* cmPart3 = (float*)alloc((size_t)4 * 262144 * 4);        // 4.2 MB
    float2* coef3 = (float2*)alloc((size_t)4 * 4096 * 8);
    float* colsum3 = (float*)alloc((size_t)4 * 4096 * 4);
    float* mean3 = (float*)alloc((size_t)4 * 4096 * 4);
    float* rg3 = (float*)alloc((size_t)4 * 4096 * 4);
    float* rt3 = (float*)alloc((size_t)4 * 4096 * 4);
    // layer4 (z=4): S=1024, C=512, R=16
    ushort_t* sim4 = (ushort_t*)alloc((size_t)4 * 1048576 * 2);    // 8.4 MB
    ushort_t* gnT4 = (ushort_t*)alloc((size_t)4 * 524288 * 2);     // 4.2 MB
    ushort_t* tnT4 = (ushort_t*)alloc((size_t)4 * 524288 * 2);     // 4.2 MB
    float* cmPart4 = (float*)alloc((size_t)4 * 16384 * 4);
    float2* coef4 = (float2*)alloc((size_t)4 * 1024 * 8);
    float* colsum4 = (float*)alloc((size_t)4 * 1024 * 4);
    float* mean4 = (float*)alloc((size_t)4 * 1024 * 4);
    float* rg4 = (float*)alloc((size_t)4 * 1024 * 4);
    float* rt4 = (float*)alloc((size_t)4 * 1024 * 4);
    float* acc = (float*)alloc(64 * 4);
    // total ~173 MB (ws is 256 MiB per the harness poison fill)

    stats_all<<<256 + 1024, 256, 0, stream>>>(
        gen3, tar3, gen4, tar4, mean3, rg3, rt3, mean4, rg4, rt4);
    apply_all<<<512 + 1024, 256, 0, stream>>>(
        gen3, tar3, gen4, tar4, mean3, rg3, rt3, mean4, rg4, rt4,
        gnT3, tnT3, gnT4, tnT4);
    gemm_all<<<256 + 4096, 256, 0, stream>>>(
        tnT3, gnT3, sim3, cmPart3, tnT4, gnT4, sim4, cmPart4);
    colmax_reduce_all<<<16 + 64, 256, 0, stream>>>(
        cmPart3, coef3, colsum3, cmPart4, coef4, colsum4, acc);
    colsum_all<<<256 + 4096, 256, 0, stream>>>(
        sim3, coef3, colsum3, sim4, coef4, colsum4);
    rowmax_all<<<1024 + 256, 256, 0, stream>>>(
        sim3, coef3, colsum3, sim4, coef4, colsum4, acc);
    finalize_kernel<<<1, 1, 0, stream>>>(acc, (float*)d_out);
}